// Round 2
// baseline (2665.277 us; speedup 1.0000x reference)
//
#include <hip/hip_runtime.h>
#include <hip/hip_bf16.h>

// HierarchicalGNN forward, FP32 in/out (per reference dtypes), MFMA bf16 core.
// h=relu(x@Wp+bp); two GATConv(+selfloops, softmax-per-dst) -> LN -> relu;
// concat @ Wf -> LN -> L2-normalize.
// N=200000, E=200000/dir, IN=HID=256, HEADS=4, C=64, OUT=128.

typedef __attribute__((ext_vector_type(8))) short bf16x8;
typedef __attribute__((ext_vector_type(4))) float f32x4;

#define HID 256
#define HEADS 4
#define CH 64

__device__ __forceinline__ float wred(float v) {
    #pragma unroll
    for (int o = 32; o > 0; o >>= 1) v += __shfl_xor(v, o, 64);
    return v;
}

__device__ __forceinline__ void atomicMaxF(float* p, float v) {
    if (v >= 0.f) atomicMax((int*)p, __float_as_int(v));
    else          atomicMin((unsigned int*)p, __float_as_uint(v));
}

// ---------------- f32 -> bf16 convert ----------------
__global__ __launch_bounds__(256) void cvt_bf16(const float* __restrict__ src,
                                                __hip_bfloat16* __restrict__ dst, long n) {
    long i = (long)blockIdx.x * 256 + threadIdx.x;
    if (i < n) dst[i] = __float2bfloat16(src[i]);
}

// ---------------- transpose+convert W[KI,KO] f32 -> Wt[KO,KI] bf16 ----------------
__global__ void transpose_w(const float* __restrict__ W,
                            __hip_bfloat16* __restrict__ Wt, int KI, int KO) {
    int idx = blockIdx.x * 256 + threadIdx.x;
    if (idx >= KI * KO) return;
    int k = idx / KO, j = idx % KO;
    Wt[(long)j * KI + k] = __float2bfloat16(W[idx]);
}

// ---------------- init float array to -3e38 ----------------
__global__ __launch_bounds__(256) void init_neg(float* __restrict__ p, long n) {
    long i = (long)blockIdx.x * 256 + threadIdx.x;
    if (i < n) p[i] = -3.0e38f;
}

// ---------------- MFMA GEMM: C[N,KO] = A[N,KI] @ Bt[KO,KI]^T ----------------
// A split across A0/A1 at kSplit (for concat); lda applies to each half.
// wave computes 16 rows x 64 cols; block = 4 waves = 64 rows x 64 cols.
__global__ __launch_bounds__(256) void gemm_mfma(
    const __hip_bfloat16* __restrict__ A0, const __hip_bfloat16* __restrict__ A1,
    int lda, int kSplit,
    const __hip_bfloat16* __restrict__ Bt, int KI, int KO,
    const float* __restrict__ bias, int doRelu,
    __hip_bfloat16* __restrict__ outB, float* __restrict__ outF) {
    int wave = threadIdx.x >> 6, lane = threadIdx.x & 63;
    int m = lane & 15, q = lane >> 4;
    long row0 = (long)blockIdx.x * 64 + wave * 16;
    int col0 = blockIdx.y * 64;
    f32x4 acc[4];
    #pragma unroll
    for (int t = 0; t < 4; ++t) acc[t] = (f32x4){0.f, 0.f, 0.f, 0.f};
    long arow = row0 + m;
    for (int k0 = 0; k0 < KI; k0 += 32) {
        const __hip_bfloat16* ap = (k0 < kSplit)
            ? A0 + arow * lda + (k0 + q * 8)
            : A1 + arow * lda + (k0 - kSplit + q * 8);
        bf16x8 av = *(const bf16x8*)ap;
        #pragma unroll
        for (int t = 0; t < 4; ++t) {
            const __hip_bfloat16* bp = Bt + (long)(col0 + t * 16 + m) * KI + (k0 + q * 8);
            bf16x8 bv = *(const bf16x8*)bp;
            acc[t] = __builtin_amdgcn_mfma_f32_16x16x32_bf16(av, bv, acc[t], 0, 0, 0);
        }
    }
    #pragma unroll
    for (int t = 0; t < 4; ++t) {
        int col = col0 + t * 16 + m;
        float bv = bias ? bias[col] : 0.f;
        #pragma unroll
        for (int r = 0; r < 4; ++r) {
            long row = row0 + q * 4 + r;
            float v = acc[t][r] + bv;
            if (doRelu) v = fmaxf(v, 0.f);
            if (outB) outB[row * KO + col] = __float2bfloat16(v);
            else      outF[row * KO + col] = v;
        }
    }
}

// ---------------- attention scores: a_src/a_dst [N,4] ----------------
__global__ __launch_bounds__(256) void att_scores(
    const __hip_bfloat16* __restrict__ hw,
    const float* __restrict__ asrc, const float* __restrict__ adst,
    float* __restrict__ a_s, float* __restrict__ a_d, int N) {
    int lane = threadIdx.x & 63;
    long node = (long)blockIdx.x * 4 + (threadIdx.x >> 6);
    if (node >= N) return;
    const __hip_bfloat16* row = hw + node * HID;
    #pragma unroll
    for (int h = 0; h < HEADS; ++h) {
        float v = (float)row[h * CH + lane];
        float ps = v * asrc[h * CH + lane];
        float pd = v * adst[h * CH + lane];
        ps = wred(ps); pd = wred(pd);
        if (lane == 0) { a_s[node * 4 + h] = ps; a_d[node * 4 + h] = pd; }
    }
}

// ---------------- edge pass A: per-dst segment max of leaky(e) ----------------
__global__ void edge_max(const int* __restrict__ ei, int E, int N,
                         const float* __restrict__ a_s, const float* __restrict__ a_d,
                         float* __restrict__ m) {
    int idx = blockIdx.x * 256 + threadIdx.x;
    if (idx >= E + N) return;
    int s, d;
    if (idx < E) { s = ei[idx]; d = ei[E + idx]; } else { s = d = idx - E; }
    #pragma unroll
    for (int h = 0; h < HEADS; ++h) {
        float e = a_s[s * 4 + h] + a_d[d * 4 + h];
        e = (e > 0.f) ? e : 0.2f * e;
        atomicMaxF(&m[d * 4 + h], e);
    }
}

// ---------------- edge pass B: ex=exp(e-m[d]); denom += ex ----------------
__global__ void edge_exp(const int* __restrict__ ei, int E, int N,
                         const float* __restrict__ a_s, const float* __restrict__ a_d,
                         const float* __restrict__ m, float* __restrict__ exbuf,
                         float* __restrict__ denom) {
    int idx = blockIdx.x * 256 + threadIdx.x;
    if (idx >= E + N) return;
    int s, d;
    if (idx < E) { s = ei[idx]; d = ei[E + idx]; } else { s = d = idx - E; }
    #pragma unroll
    for (int h = 0; h < HEADS; ++h) {
        float e = a_s[s * 4 + h] + a_d[d * 4 + h];
        e = (e > 0.f) ? e : 0.2f * e;
        float ex = __expf(fminf(e - m[d * 4 + h], 0.f));
        exbuf[(long)idx * 4 + h] = ex;
        atomicAdd(&denom[d * 4 + h], ex);
    }
}

// ---------------- edge pass C: acc[d,c] += hw[s,c] * alpha ----------------
__global__ __launch_bounds__(256) void edge_agg(
    const int* __restrict__ ei, int E, int N,
    const __hip_bfloat16* __restrict__ hw, const float* __restrict__ exbuf,
    const float* __restrict__ denom, float* __restrict__ acc) {
    long idx = blockIdx.x;
    int c = threadIdx.x;
    int s, d;
    if (idx < E) { s = ei[idx]; d = ei[E + idx]; } else { s = d = (int)(idx - E); }
    int h = c >> 6;
    float alpha = exbuf[idx * 4 + h] / denom[(long)d * 4 + h];
    float v = (float)hw[(long)s * HID + c] * alpha;
    atomicAdd(&acc[(long)d * HID + c], v);
}

// ---------------- LN(+bias) + relu over 256 -> bf16 ----------------
__global__ __launch_bounds__(256) void ln_relu(
    const float* __restrict__ acc, const float* __restrict__ bias,
    const float* __restrict__ g, const float* __restrict__ b,
    __hip_bfloat16* __restrict__ out, int N) {
    int lane = threadIdx.x & 63;
    long row = (long)blockIdx.x * 4 + (threadIdx.x >> 6);
    if (row >= N) return;
    const float* a = acc + row * HID;
    float v[4]; float s = 0.f;
    #pragma unroll
    for (int i = 0; i < 4; ++i) {
        v[i] = a[i * 64 + lane] + bias[i * 64 + lane];
        s += v[i];
    }
    float mean = wred(s) * (1.f / 256.f);
    float qs = 0.f;
    #pragma unroll
    for (int i = 0; i < 4; ++i) { v[i] -= mean; qs += v[i] * v[i]; }
    float var = wred(qs) * (1.f / 256.f);
    float inv = rsqrtf(var + 1e-5f);
    #pragma unroll
    for (int i = 0; i < 4; ++i) {
        float y = v[i] * inv * g[i * 64 + lane] + b[i * 64 + lane];
        out[row * HID + i * 64 + lane] = __float2bfloat16(fmaxf(y, 0.f));
    }
}

// ---------------- final: +bf -> LN(128) -> L2 normalize -> f32 out ----------------
__global__ __launch_bounds__(256) void final_ln_norm(
    const float* __restrict__ tmp, const float* __restrict__ bfv,
    const float* __restrict__ g, const float* __restrict__ b,
    float* __restrict__ out, int N) {
    int lane = threadIdx.x & 63;
    long row = (long)blockIdx.x * 4 + (threadIdx.x >> 6);
    if (row >= N) return;
    float v0 = tmp[row * 128 + lane] + bfv[lane];
    float v1 = tmp[row * 128 + 64 + lane] + bfv[64 + lane];
    float mean = wred(v0 + v1) * (1.f / 128.f);
    v0 -= mean; v1 -= mean;
    float var = wred(v0 * v0 + v1 * v1) * (1.f / 128.f);
    float inv = rsqrtf(var + 1e-5f);
    float y0 = v0 * inv * g[lane] + b[lane];
    float y1 = v1 * inv * g[64 + lane] + b[64 + lane];
    float nrm = sqrtf(wred(y0 * y0 + y1 * y1));
    float sc = 1.f / fmaxf(nrm, 1e-12f);
    out[row * 128 + lane] = y0 * sc;
    out[row * 128 + 64 + lane] = y1 * sc;
}

extern "C" void kernel_launch(void* const* d_in, const int* in_sizes, int n_in,
                              void* d_out, int out_size, void* d_ws, size_t ws_size,
                              hipStream_t stream) {
    const float* x      = (const float*)d_in[0];
    const int*   ei_bu  = (const int*)d_in[1];
    const int*   ei_td  = (const int*)d_in[2];
    const float* Wp     = (const float*)d_in[3];
    const float* bp     = (const float*)d_in[4];
    const float* W_bu   = (const float*)d_in[5];
    const float* asrc_bu= (const float*)d_in[6];
    const float* adst_bu= (const float*)d_in[7];
    const float* bias_bu= (const float*)d_in[8];
    const float* W_td   = (const float*)d_in[9];
    const float* asrc_td= (const float*)d_in[10];
    const float* adst_td= (const float*)d_in[11];
    const float* bias_td= (const float*)d_in[12];
    const float* Wf     = (const float*)d_in[13];
    const float* bfv    = (const float*)d_in[14];
    const float* g_bu   = (const float*)d_in[15];
    const float* b_bu   = (const float*)d_in[16];
    const float* g_td   = (const float*)d_in[17];
    const float* b_td   = (const float*)d_in[18];
    const float* g_out  = (const float*)d_in[19];
    const float* b_out  = (const float*)d_in[20];

    const int N = in_sizes[0] / HID;   // 200000
    const int E = in_sizes[1] / 2;     // 200000

    char* ws = (char*)d_ws;
    size_t off = 0;
    auto take = [&](size_t bytes) -> char* {
        char* p = ws + off;
        off += (bytes + 255) & ~(size_t)255;
        return p;
    };
    __hip_bfloat16* xbf   = (__hip_bfloat16*)take((size_t)N * HID * 2); // aliased as hw later
    __hip_bfloat16* h_buf = (__hip_bfloat16*)take((size_t)N * HID * 2);
    __hip_bfloat16* xbu   = (__hip_bfloat16*)take((size_t)N * HID * 2);
    __hip_bfloat16* xtd   = (__hip_bfloat16*)take((size_t)N * HID * 2);
    float* acc   = (float*)take((size_t)N * HID * 4);   // reused as final GEMM tmp [N,128]
    float* a_s   = (float*)take((size_t)N * 16);
    float* a_d   = (float*)take((size_t)N * 16);
    float* mbuf  = (float*)take((size_t)N * 16);
    float* denom = (float*)take((size_t)N * 16);
    float* exbuf = (float*)take((size_t)(E + N) * 16);
    __hip_bfloat16* Wpt  = (__hip_bfloat16*)take(256 * 256 * 2);
    __hip_bfloat16* Wbut = (__hip_bfloat16*)take(256 * 256 * 2);
    __hip_bfloat16* Wtdt = (__hip_bfloat16*)take(256 * 256 * 2);
    __hip_bfloat16* Wft  = (__hip_bfloat16*)take(512 * 128 * 2);
    __hip_bfloat16* hw = xbf;  // xbf dead after first GEMM

    // weight transposes + input convert (f32 -> bf16)
    transpose_w<<<(256 * 256 + 255) / 256, 256, 0, stream>>>(Wp, Wpt, 256, 256);
    transpose_w<<<(256 * 256 + 255) / 256, 256, 0, stream>>>(W_bu, Wbut, 256, 256);
    transpose_w<<<(256 * 256 + 255) / 256, 256, 0, stream>>>(W_td, Wtdt, 256, 256);
    transpose_w<<<(512 * 128 + 255) / 256, 256, 0, stream>>>(Wf, Wft, 512, 128);
    long nx = (long)N * HID;
    cvt_bf16<<<(nx + 255) / 256, 256, 0, stream>>>(x, xbf, nx);

    // h = relu(x @ Wp + bp)
    dim3 g256((N + 63) / 64, HID / 64);
    gemm_mfma<<<g256, 256, 0, stream>>>(xbf, xbf, HID, HID, Wpt, HID, HID, bp, 1, h_buf, nullptr);

    const int* eis[2] = {ei_bu, ei_td};
    const __hip_bfloat16* Wts[2] = {Wbut, Wtdt};
    const float* asrcs[2] = {asrc_bu, asrc_td};
    const float* adsts[2] = {adst_bu, adst_td};
    const float* biases[2]= {bias_bu, bias_td};
    const float* gs[2]    = {g_bu, g_td};
    const float* bs[2]    = {b_bu, b_td};
    __hip_bfloat16* xouts[2] = {xbu, xtd};

    int egrid = (E + N + 255) / 256;
    long nm = (long)N * 4;
    for (int dir = 0; dir < 2; ++dir) {
        gemm_mfma<<<g256, 256, 0, stream>>>(h_buf, h_buf, HID, HID, Wts[dir], HID, HID,
                                            nullptr, 0, hw, nullptr);
        att_scores<<<(N + 3) / 4, 256, 0, stream>>>(hw, asrcs[dir], adsts[dir], a_s, a_d, N);
        init_neg<<<(nm + 255) / 256, 256, 0, stream>>>(mbuf, nm);
        hipMemsetAsync(denom, 0, (size_t)N * 16, stream);
        hipMemsetAsync(acc, 0, (size_t)N * HID * 4, stream);
        edge_max<<<egrid, 256, 0, stream>>>(eis[dir], E, N, a_s, a_d, mbuf);
        edge_exp<<<egrid, 256, 0, stream>>>(eis[dir], E, N, a_s, a_d, mbuf, exbuf, denom);
        edge_agg<<<E + N, 256, 0, stream>>>(eis[dir], E, N, hw, exbuf, denom, acc);
        ln_relu<<<(N + 3) / 4, 256, 0, stream>>>(acc, biases[dir], gs[dir], bs[dir], xouts[dir], N);
    }

    // final: tmp = [xbu|xtd] @ Wf (f32), then +bf -> LN -> L2norm -> out
    float* tmp = acc;
    dim3 gf((N + 63) / 64, 128 / 64);
    gemm_mfma<<<gf, 256, 0, stream>>>(xbu, xtd, HID, HID, Wft, 512, 128,
                                      nullptr, 0, nullptr, tmp);
    final_ln_norm<<<(N + 3) / 4, 256, 0, stream>>>(tmp, bfv, g_out, b_out,
                                                   (float*)d_out, N);
}

// Round 4
// 1968.859 us; speedup vs baseline: 1.3537x; 1.3537x over previous
//
#include <hip/hip_runtime.h>
#include <hip/hip_bf16.h>

// HierarchicalGNN forward, FP32 in/out, MFMA bf16 GEMMs, CSR-gather GAT (no f32 atomics).
// h=relu(x@Wp+bp); two GATConv(+selfloops, softmax-per-dst) -> LN -> relu;
// concat @ Wf -> LN -> L2-normalize.
// N=200000, E=200000/dir, IN=HID=256, HEADS=4, C=64, OUT=128.

typedef __attribute__((ext_vector_type(8))) short bf16x8;
typedef __attribute__((ext_vector_type(4))) short bf16x4;
typedef __attribute__((ext_vector_type(4))) float f32x4;

#define HID 256
#define HEADS 4
#define CH 64

__device__ __forceinline__ float wred(float v) {
    #pragma unroll
    for (int o = 32; o > 0; o >>= 1) v += __shfl_xor(v, o, 64);
    return v;
}
__device__ __forceinline__ float wredmax(float v) {
    #pragma unroll
    for (int o = 32; o > 0; o >>= 1) v = fmaxf(v, __shfl_xor(v, o, 64));
    return v;
}
__device__ __forceinline__ float bf2f(short s) {
    return __uint_as_float(((unsigned)(unsigned short)s) << 16);
}
__device__ __forceinline__ float sel4(float a0, float a1, float a2, float a3, int h) {
    return h == 0 ? a0 : (h == 1 ? a1 : (h == 2 ? a2 : a3));
}

// ---------------- f32 -> bf16 convert ----------------
__global__ __launch_bounds__(256) void cvt_bf16(const float* __restrict__ src,
                                                __hip_bfloat16* __restrict__ dst, long n) {
    long i = (long)blockIdx.x * 256 + threadIdx.x;
    if (i < n) dst[i] = __float2bfloat16(src[i]);
}

// ---------------- transpose+convert W[KI,KO] f32 -> Wt[KO,KI] bf16 ----------------
__global__ void transpose_w(const float* __restrict__ W,
                            __hip_bfloat16* __restrict__ Wt, int KI, int KO) {
    int idx = blockIdx.x * 256 + threadIdx.x;
    if (idx >= KI * KO) return;
    int k = idx / KO, j = idx % KO;
    Wt[(long)j * KI + k] = __float2bfloat16(W[idx]);
}

// ---------------- MFMA GEMM: C[N,KO] = A[N,KI] @ Bt[KO,KI]^T ----------------
__global__ __launch_bounds__(256) void gemm_mfma(
    const __hip_bfloat16* __restrict__ A0, const __hip_bfloat16* __restrict__ A1,
    int lda, int kSplit,
    const __hip_bfloat16* __restrict__ Bt, int KI, int KO,
    const float* __restrict__ bias, int doRelu,
    __hip_bfloat16* __restrict__ outB, float* __restrict__ outF) {
    int wave = threadIdx.x >> 6, lane = threadIdx.x & 63;
    int m = lane & 15, q = lane >> 4;
    long row0 = (long)blockIdx.x * 64 + wave * 16;
    int col0 = blockIdx.y * 64;
    f32x4 acc[4];
    #pragma unroll
    for (int t = 0; t < 4; ++t) acc[t] = (f32x4){0.f, 0.f, 0.f, 0.f};
    long arow = row0 + m;
    for (int k0 = 0; k0 < KI; k0 += 32) {
        const __hip_bfloat16* ap = (k0 < kSplit)
            ? A0 + arow * lda + (k0 + q * 8)
            : A1 + arow * lda + (k0 - kSplit + q * 8);
        bf16x8 av = *(const bf16x8*)ap;
        #pragma unroll
        for (int t = 0; t < 4; ++t) {
            const __hip_bfloat16* bp = Bt + (long)(col0 + t * 16 + m) * KI + (k0 + q * 8);
            bf16x8 bv = *(const bf16x8*)bp;
            acc[t] = __builtin_amdgcn_mfma_f32_16x16x32_bf16(av, bv, acc[t], 0, 0, 0);
        }
    }
    #pragma unroll
    for (int t = 0; t < 4; ++t) {
        int col = col0 + t * 16 + m;
        float bv = bias ? bias[col] : 0.f;
        #pragma unroll
        for (int r = 0; r < 4; ++r) {
            long row = row0 + q * 4 + r;
            float v = acc[t][r] + bv;
            if (doRelu) v = fmaxf(v, 0.f);
            if (outB) outB[row * KO + col] = __float2bfloat16(v);
            else      outF[row * KO + col] = v;
        }
    }
}

// ---------------- attention scores: a_src/a_dst [N,4] ----------------
__global__ __launch_bounds__(256) void att_scores(
    const __hip_bfloat16* __restrict__ hw,
    const float* __restrict__ asrc, const float* __restrict__ adst,
    float* __restrict__ a_s, float* __restrict__ a_d, int N) {
    int lane = threadIdx.x & 63;
    long node = (long)blockIdx.x * 4 + (threadIdx.x >> 6);
    if (node >= N) return;
    const __hip_bfloat16* row = hw + node * HID;
    #pragma unroll
    for (int h = 0; h < HEADS; ++h) {
        float v = (float)row[h * CH + lane];
        float ps = v * asrc[h * CH + lane];
        float pd = v * adst[h * CH + lane];
        ps = wred(ps); pd = wred(pd);
        if (lane == 0) { a_s[node * 4 + h] = ps; a_d[node * 4 + h] = pd; }
    }
}

// ---------------- CSR build ----------------
__global__ __launch_bounds__(256) void hist_dst(const int* __restrict__ ei, int E,
                                                int* __restrict__ cnt) {
    int e = blockIdx.x * 256 + threadIdx.x;
    if (e < E) atomicAdd(&cnt[ei[E + e]], 1);
}

// exclusive scan within 256-chunks; bsum[b] = chunk total
__global__ __launch_bounds__(256) void scan1(const int* __restrict__ cnt,
                                             int* __restrict__ offpart,
                                             int* __restrict__ bsum, int n) {
    int t = threadIdx.x, i = blockIdx.x * 256 + t;
    int lane = t & 63, w = t >> 6;
    int v = (i < n) ? cnt[i] : 0;
    int inc = v;
    #pragma unroll
    for (int o = 1; o < 64; o <<= 1) {
        int u = __shfl_up(inc, o, 64);
        if (lane >= o) inc += u;
    }
    __shared__ int wsum[4];
    if (lane == 63) wsum[w] = inc;
    __syncthreads();
    int wadd = 0;
    #pragma unroll
    for (int k = 0; k < 4; ++k) if (k < w) wadd += wsum[k];
    if (i < n) offpart[i] = inc - v + wadd;
    if (t == 255) bsum[blockIdx.x] = inc + wadd;
}

// exclusive scan of up to 1024 block sums, single block of 256 threads
__global__ __launch_bounds__(256) void scan2(const int* __restrict__ bsum,
                                             int* __restrict__ btot, int nb) {
    int t = threadIdx.x, lane = t & 63, w = t >> 6;
    int loc[4]; int s = 0;
    #pragma unroll
    for (int k = 0; k < 4; ++k) {
        int idx = t * 4 + k;
        int v = (idx < nb) ? bsum[idx] : 0;
        loc[k] = s; s += v;
    }
    int inc = s;
    #pragma unroll
    for (int o = 1; o < 64; o <<= 1) {
        int u = __shfl_up(inc, o, 64);
        if (lane >= o) inc += u;
    }
    __shared__ int wsum[4];
    if (lane == 63) wsum[w] = inc;
    __syncthreads();
    int wadd = 0;
    #pragma unroll
    for (int k = 0; k < 4; ++k) if (k < w) wadd += wsum[k];
    int excl = inc - s + wadd;
    #pragma unroll
    for (int k = 0; k < 4; ++k) {
        int idx = t * 4 + k;
        if (idx < nb) btot[idx] = excl + loc[k];
    }
}

__global__ __launch_bounds__(256) void finalize_off(const int* __restrict__ offpart,
                                                    const int* __restrict__ btot,
                                                    int* __restrict__ off, int n, int E) {
    int i = blockIdx.x * 256 + threadIdx.x;
    if (i < n) off[i] = offpart[i] + btot[i >> 8];
    if (i == 0) off[n] = E;
}

__global__ __launch_bounds__(256) void scatter_src(const int* __restrict__ ei, int E,
                                                   const int* __restrict__ off,
                                                   int* __restrict__ cur,
                                                   int* __restrict__ esrc) {
    int e = blockIdx.x * 256 + threadIdx.x;
    if (e >= E) return;
    int d = ei[E + e];
    int pos = off[d] + atomicAdd(&cur[d], 1);
    esrc[pos] = ei[e];
}

// ---------------- fused GAT: softmax + gather + bias + LN + relu ----------------
// one wave per dst node; lane holds 4 contiguous channels c = lane*4..lane*4+3 (head = lane>>4).
__global__ __launch_bounds__(256) void gat_fused(
    const int* __restrict__ off, const int* __restrict__ esrc,
    const float* __restrict__ a_s, const float* __restrict__ a_d,
    const __hip_bfloat16* __restrict__ hw,
    const float* __restrict__ bias, const float* __restrict__ g,
    const float* __restrict__ b,
    __hip_bfloat16* __restrict__ out, int N) {
    int lane = threadIdx.x & 63;
    long d = (long)blockIdx.x * 4 + (threadIdx.x >> 6);
    if (d >= N) return;
    int beg = off[d], end = off[d + 1];
    f32x4 adv = *(const f32x4*)(a_d + 4 * d);
    f32x4 asd = *(const f32x4*)(a_s + 4 * d);
    float es0, es1, es2, es3;
    {
        float e;
        e = asd[0] + adv[0]; es0 = e > 0.f ? e : 0.2f * e;
        e = asd[1] + adv[1]; es1 = e > 0.f ? e : 0.2f * e;
        e = asd[2] + adv[2]; es2 = e > 0.f ? e : 0.2f * e;
        e = asd[3] + adv[3]; es3 = e > 0.f ? e : 0.2f * e;
    }
    // pass 1: per-head max over edges (lanes parallel over edges)
    float m0 = -3e38f, m1 = -3e38f, m2 = -3e38f, m3 = -3e38f;
    for (int j = beg + lane; j < end; j += 64) {
        int s = esrc[j];
        f32x4 asv = *(const f32x4*)(a_s + 4 * (long)s);
        float e;
        e = asv[0] + adv[0]; e = e > 0.f ? e : 0.2f * e; m0 = fmaxf(m0, e);
        e = asv[1] + adv[1]; e = e > 0.f ? e : 0.2f * e; m1 = fmaxf(m1, e);
        e = asv[2] + adv[2]; e = e > 0.f ? e : 0.2f * e; m2 = fmaxf(m2, e);
        e = asv[3] + adv[3]; e = e > 0.f ? e : 0.2f * e; m3 = fmaxf(m3, e);
    }
    m0 = fmaxf(wredmax(m0), es0); m1 = fmaxf(wredmax(m1), es1);
    m2 = fmaxf(wredmax(m2), es2); m3 = fmaxf(wredmax(m3), es3);
    // pass 2: per-head sum of exp
    float s0 = 0.f, s1 = 0.f, s2 = 0.f, s3 = 0.f;
    for (int j = beg + lane; j < end; j += 64) {
        int s = esrc[j];
        f32x4 asv = *(const f32x4*)(a_s + 4 * (long)s);
        float e;
        e = asv[0] + adv[0]; e = e > 0.f ? e : 0.2f * e; s0 += __expf(e - m0);
        e = asv[1] + adv[1]; e = e > 0.f ? e : 0.2f * e; s1 += __expf(e - m1);
        e = asv[2] + adv[2]; e = e > 0.f ? e : 0.2f * e; s2 += __expf(e - m2);
        e = asv[3] + adv[3]; e = e > 0.f ? e : 0.2f * e; s3 += __expf(e - m3);
    }
    s0 = wred(s0) + __expf(es0 - m0); s1 = wred(s1) + __expf(es1 - m1);
    s2 = wred(s2) + __expf(es2 - m2); s3 = wred(s3) + __expf(es3 - m3);
    // pass 3: alpha-weighted gather; lane's head
    int h4 = lane >> 4;
    int c0 = lane * 4;
    float mh = sel4(m0, m1, m2, m3, h4);
    float rsh = 1.f / sel4(s0, s1, s2, s3, h4);
    float adh = adv[h4];
    float acc0, acc1, acc2, acc3;
    {   // self loop
        float alpha = __expf(sel4(es0, es1, es2, es3, h4) - mh) * rsh;
        bf16x4 hv = *(const bf16x4*)(hw + d * HID + c0);
        acc0 = alpha * bf2f(hv[0]); acc1 = alpha * bf2f(hv[1]);
        acc2 = alpha * bf2f(hv[2]); acc3 = alpha * bf2f(hv[3]);
    }
    for (int j = beg; j < end; ++j) {
        int s = esrc[j];                       // uniform across wave
        float as_h = a_s[4 * (long)s + h4];
        float e = as_h + adh; e = e > 0.f ? e : 0.2f * e;
        float alpha = __expf(e - mh) * rsh;
        bf16x4 hv = *(const bf16x4*)(hw + (long)s * HID + c0);
        acc0 += alpha * bf2f(hv[0]); acc1 += alpha * bf2f(hv[1]);
        acc2 += alpha * bf2f(hv[2]); acc3 += alpha * bf2f(hv[3]);
    }
    // fused bias + LN + relu
    f32x4 bi = *(const f32x4*)(bias + c0);
    acc0 += bi[0]; acc1 += bi[1]; acc2 += bi[2]; acc3 += bi[3];
    float mean = wred(acc0 + acc1 + acc2 + acc3) * (1.f / 256.f);
    acc0 -= mean; acc1 -= mean; acc2 -= mean; acc3 -= mean;
    float var = wred(acc0 * acc0 + acc1 * acc1 + acc2 * acc2 + acc3 * acc3) * (1.f / 256.f);
    float inv = rsqrtf(var + 1e-5f);
    f32x4 gv = *(const f32x4*)(g + c0);
    f32x4 bv = *(const f32x4*)(b + c0);
    __hip_bfloat16 t0 = __float2bfloat16(fmaxf(acc0 * inv * gv[0] + bv[0], 0.f));
    __hip_bfloat16 t1 = __float2bfloat16(fmaxf(acc1 * inv * gv[1] + bv[1], 0.f));
    __hip_bfloat16 t2 = __float2bfloat16(fmaxf(acc2 * inv * gv[2] + bv[2], 0.f));
    __hip_bfloat16 t3 = __float2bfloat16(fmaxf(acc3 * inv * gv[3] + bv[3], 0.f));
    __hip_bfloat16* orow = out + d * HID + c0;
    orow[0] = t0; orow[1] = t1; orow[2] = t2; orow[3] = t3;
}

// ---------------- final: +bf -> LN(128) -> L2 normalize -> f32 out ----------------
__global__ __launch_bounds__(256) void final_ln_norm(
    const float* __restrict__ tmp, const float* __restrict__ bfv,
    const float* __restrict__ g, const float* __restrict__ b,
    float* __restrict__ out, int N) {
    int lane = threadIdx.x & 63;
    long row = (long)blockIdx.x * 4 + (threadIdx.x >> 6);
    if (row >= N) return;
    float v0 = tmp[row * 128 + lane] + bfv[lane];
    float v1 = tmp[row * 128 + 64 + lane] + bfv[64 + lane];
    float mean = wred(v0 + v1) * (1.f / 128.f);
    v0 -= mean; v1 -= mean;
    float var = wred(v0 * v0 + v1 * v1) * (1.f / 128.f);
    float inv = rsqrtf(var + 1e-5f);
    float y0 = v0 * inv * g[lane] + b[lane];
    float y1 = v1 * inv * g[64 + lane] + b[64 + lane];
    float nrm = sqrtf(wred(y0 * y0 + y1 * y1));
    float sc = 1.f / fmaxf(nrm, 1e-12f);
    out[row * 128 + lane] = y0 * sc;
    out[row * 128 + 64 + lane] = y1 * sc;
}

extern "C" void kernel_launch(void* const* d_in, const int* in_sizes, int n_in,
                              void* d_out, int out_size, void* d_ws, size_t ws_size,
                              hipStream_t stream) {
    const float* x      = (const float*)d_in[0];
    const int*   ei_bu  = (const int*)d_in[1];
    const int*   ei_td  = (const int*)d_in[2];
    const float* Wp     = (const float*)d_in[3];
    const float* bp     = (const float*)d_in[4];
    const float* W_bu   = (const float*)d_in[5];
    const float* asrc_bu= (const float*)d_in[6];
    const float* adst_bu= (const float*)d_in[7];
    const float* bias_bu= (const float*)d_in[8];
    const float* W_td   = (const float*)d_in[9];
    const float* asrc_td= (const float*)d_in[10];
    const float* adst_td= (const float*)d_in[11];
    const float* bias_td= (const float*)d_in[12];
    const float* Wf     = (const float*)d_in[13];
    const float* bfv    = (const float*)d_in[14];
    const float* g_bu   = (const float*)d_in[15];
    const float* b_bu   = (const float*)d_in[16];
    const float* g_td   = (const float*)d_in[17];
    const float* b_td   = (const float*)d_in[18];
    const float* g_out  = (const float*)d_in[19];
    const float* b_out  = (const float*)d_in[20];

    const int N = in_sizes[0] / HID;   // 200000
    const int E = in_sizes[1] / 2;     // 200000

    char* ws = (char*)d_ws;
    size_t off0 = 0;
    auto take = [&](size_t bytes) -> char* {
        char* p = ws + off0;
        off0 += (bytes + 255) & ~(size_t)255;
        return p;
    };
    __hip_bfloat16* xbf   = (__hip_bfloat16*)take((size_t)N * HID * 2); // aliased as hw later
    __hip_bfloat16* h_buf = (__hip_bfloat16*)take((size_t)N * HID * 2);
    __hip_bfloat16* xbu   = (__hip_bfloat16*)take((size_t)N * HID * 2);
    __hip_bfloat16* xtd   = (__hip_bfloat16*)take((size_t)N * HID * 2);
    float* tmp   = (float*)take((size_t)N * 128 * 4);   // final GEMM f32 out
    float* a_s   = (float*)take((size_t)N * 16);
    float* a_d   = (float*)take((size_t)N * 16);
    int* cnt     = (int*)take((size_t)N * 4);
    int* offpart = (int*)take((size_t)N * 4);
    int* offarr  = (int*)take((size_t)(N + 1) * 4);
    int* cur     = (int*)take((size_t)N * 4);
    int* esrc    = (int*)take((size_t)E * 4);
    int* bsum    = (int*)take(1024 * 4);
    int* btot    = (int*)take(1024 * 4);
    __hip_bfloat16* Wpt  = (__hip_bfloat16*)take(256 * 256 * 2);
    __hip_bfloat16* Wbut = (__hip_bfloat16*)take(256 * 256 * 2);
    __hip_bfloat16* Wtdt = (__hip_bfloat16*)take(256 * 256 * 2);
    __hip_bfloat16* Wft  = (__hip_bfloat16*)take(512 * 128 * 2);
    __hip_bfloat16* hw = xbf;  // xbf dead after first GEMM

    transpose_w<<<(256 * 256 + 255) / 256, 256, 0, stream>>>(Wp, Wpt, 256, 256);
    transpose_w<<<(256 * 256 + 255) / 256, 256, 0, stream>>>(W_bu, Wbut, 256, 256);
    transpose_w<<<(256 * 256 + 255) / 256, 256, 0, stream>>>(W_td, Wtdt, 256, 256);
    transpose_w<<<(512 * 128 + 255) / 256, 256, 0, stream>>>(Wf, Wft, 512, 128);
    long nx = (long)N * HID;
    cvt_bf16<<<(nx + 255) / 256, 256, 0, stream>>>(x, xbf, nx);

    // h = relu(x @ Wp + bp)
    dim3 g256((N + 63) / 64, HID / 64);
    gemm_mfma<<<g256, 256, 0, stream>>>(xbf, xbf, HID, HID, Wpt, HID, HID, bp, 1, h_buf, nullptr);

    const int* eis[2] = {ei_bu, ei_td};
    const __hip_bfloat16* Wts[2] = {Wbut, Wtdt};
    const float* asrcs[2] = {asrc_bu, asrc_td};
    const float* adsts[2] = {adst_bu, adst_td};
    const float* biases[2]= {bias_bu, bias_td};
    const float* gs[2]    = {g_bu, g_td};
    const float* bs[2]    = {b_bu, b_td};
    __hip_bfloat16* xouts[2] = {xbu, xtd};

    int egrid = (E + 255) / 256;
    int ngrid = (N + 255) / 256;
    int nb = (N + 255) / 256;
    for (int dir = 0; dir < 2; ++dir) {
        gemm_mfma<<<g256, 256, 0, stream>>>(h_buf, h_buf, HID, HID, Wts[dir], HID, HID,
                                            nullptr, 0, hw, nullptr);
        att_scores<<<(N + 3) / 4, 256, 0, stream>>>(hw, asrcs[dir], adsts[dir], a_s, a_d, N);
        // CSR build
        hipMemsetAsync(cnt, 0, (size_t)N * 4, stream);
        hipMemsetAsync(cur, 0, (size_t)N * 4, stream);
        hist_dst<<<egrid, 256, 0, stream>>>(eis[dir], E, cnt);
        scan1<<<nb, 256, 0, stream>>>(cnt, offpart, bsum, N);
        scan2<<<1, 256, 0, stream>>>(bsum, btot, nb);
        finalize_off<<<ngrid, 256, 0, stream>>>(offpart, btot, offarr, N, E);
        scatter_src<<<egrid, 256, 0, stream>>>(eis[dir], E, offarr, cur, esrc);
        // fused GAT + bias + LN + relu
        gat_fused<<<(N + 3) / 4, 256, 0, stream>>>(offarr, esrc, a_s, a_d, hw,
                                                   biases[dir], gs[dir], bs[dir],
                                                   xouts[dir], N);
    }

    // final: tmp = [xbu|xtd] @ Wf (f32), then +bf -> LN -> L2norm -> out
    dim3 gf((N + 63) / 64, 128 / 64);
    gemm_mfma<<<gf, 256, 0, stream>>>(xbu, xtd, HID, HID, Wft, 512, 128,
                                      nullptr, 0, nullptr, tmp);
    final_ln_norm<<<(N + 3) / 4, 256, 0, stream>>>(tmp, bfv, g_out, b_out,
                                                   (float*)d_out, N);
}